// Round 5
// baseline (350.896 us; speedup 1.0000x reference)
//
#include <hip/hip_runtime.h>
#include <math.h>

#define TPB 256

// ---- LDS layout (float offsets), lifetime-overlaid. Weights in GLOBAL/L2. ----
// timeline: x[1-7] c1[2-4] P5[3-4] f/h/k[4-7] y[7-8] c3[8-10] p3[10-11] pf[11-12]
#define OX    0       // 784   x image (conv7 + dyn conv read it)
#define OC1   784     // 968   conv7 pooled out [8,11,11]
#define OP5   1752    // 2880  conv5 partials (dead after reduce)
#define OF    4632    // 90
#define OH    4722    // 32
#define OK2   4754    // 40    dynamic kernels (alive till dyn conv)
#define OY    784     // 1690  dyn out [10,13,13] (c1/P5 dead)  [784,2474)
#define OC3   2474    // 1620  conv2 out [20,9,9]               [2474,4094)
#define OP3   0       // 320   pooled conv2 (x dead)            [0,320)
#define OPF   320     // 250   fc320 partials                   [320,570)
#define OA1   570     // 50
#define OZ    620     // 10
#define SM_TOT 4794   // 19176 B -> 8 blocks/CU = 32 waves (occupancy cap)

// NOTE: no min-waves launch bound — R3 showed (256,5) forces VGPR=48 + scratch
// spill (WRITE_SIZE 0.5->237 MB). Natural allocation is ~60 VGPR.
__global__ __launch_bounds__(TPB) void fused_forward(
    const float* __restrict__ x,
    const float* __restrict__ kf_w1, const float* __restrict__ kf_b1,
    const float* __restrict__ kf_w2, const float* __restrict__ kf_b2,
    const float* __restrict__ kf_fc1_w, const float* __restrict__ kf_fc1_b,
    const float* __restrict__ kf_fc2_w, const float* __restrict__ kf_fc2_b,
    const float* __restrict__ conv2_w, const float* __restrict__ conv2_b,
    const float* __restrict__ fc1_w, const float* __restrict__ fc1_b,
    const float* __restrict__ fc2_w, const float* __restrict__ fc2_b,
    float* __restrict__ out)
{
    __shared__ float sm[SM_TOT];
    const int tid = threadIdx.x;
    const int n = blockIdx.x;

    // ---- stage 0: stage x into LDS (float4) ----
    {
        const float4* xg = (const float4*)(x + (long long)n * 784);
        float4* d = (float4*)&sm[OX];
        for (int i = tid; i < 196; i += TPB) d[i] = xg[i];
    }
    __syncthreads();

    // ---- conv7 (28->22) + pool (->11) + relu ----
    // thread = (half, oc, py): 6 pooled outputs (halves overlap at px=5 with
    // bitwise-identical values -> benign double write).
    if (tid < 176) {
        int h = tid / 88, r2 = tid % 88;
        int oc = r2 / 11, py = r2 % 11;
        int cc0 = 10 * h;
        float c[2][12];
        #pragma unroll
        for (int r = 0; r < 2; ++r)
            #pragma unroll
            for (int i = 0; i < 12; ++i) c[r][i] = 0.f;
        float wc[7], wp[7];
        const float* wg = kf_w1 + oc * 49;
        #pragma unroll
        for (int i = 0; i < 7; ++i) wc[i] = wg[i];
        #pragma unroll
        for (int t = 0; t < 8; ++t) {
            const float* xs = &sm[OX + (2 * py + t) * 28 + cc0];
            float row[18];
            #pragma unroll
            for (int i = 0; i < 18; ++i) row[i] = xs[i];
            if (t <= 6) {
                #pragma unroll
                for (int kx = 0; kx < 7; ++kx)
                    #pragma unroll
                    for (int cc = 0; cc < 12; ++cc)
                        c[0][cc] = fmaf(wc[kx], row[cc + kx], c[0][cc]);
            }
            if (t >= 1) {
                #pragma unroll
                for (int kx = 0; kx < 7; ++kx)
                    #pragma unroll
                    for (int cc = 0; cc < 12; ++cc)
                        c[1][cc] = fmaf(wp[kx], row[cc + kx], c[1][cc]);
            }
            #pragma unroll
            for (int i = 0; i < 7; ++i) wp[i] = wc[i];
            if (t < 7) {
                const float* wn = wg + (t + 1) * 7;
                #pragma unroll
                for (int i = 0; i < 7; ++i) wc[i] = wn[i];
            }
        }
        float b = kf_b1[oc];
        #pragma unroll
        for (int j = 0; j < 6; ++j) {
            float m = fmaxf(fmaxf(c[0][2 * j], c[0][2 * j + 1]),
                            fmaxf(c[1][2 * j], c[1][2 * j + 1]));
            sm[OC1 + oc * 121 + py * 11 + 5 * h + j] = fmaxf(m + b, 0.f);
        }
    }
    __syncthreads();

    // ---- conv5: thread = (row-half, oc, ic) computes 3x6 conv partial ----
    if (tid < 160) {
        int hh = tid / 80, rem = tid % 80;
        int oc = rem / 8, ic = rem % 8;
        int r0 = 3 * hh;
        float w[25];
        const float* wg = kf_w2 + (oc * 8 + ic) * 25;
        #pragma unroll
        for (int i = 0; i < 25; ++i) w[i] = wg[i];
        float acc[3][6];
        #pragma unroll
        for (int r = 0; r < 3; ++r)
            #pragma unroll
            for (int i = 0; i < 6; ++i) acc[r][i] = 0.f;
        const float* xb = &sm[OC1 + ic * 121];
        #pragma unroll
        for (int u = 0; u < 7; ++u) {
            const float* xs = xb + (r0 + u) * 11;
            float row[10];
            #pragma unroll
            for (int i = 0; i < 10; ++i) row[i] = xs[i];
            #pragma unroll
            for (int rr = 0; rr < 3; ++rr) {
                int ky = u - rr;
                if (ky >= 0 && ky <= 4) {
                    #pragma unroll
                    for (int kx = 0; kx < 5; ++kx)
                        #pragma unroll
                        for (int cx = 0; cx < 6; ++cx)
                            acc[rr][cx] = fmaf(w[ky * 5 + kx], row[cx + kx], acc[rr][cx]);
                }
            }
        }
        #pragma unroll
        for (int rr = 0; rr < 3; ++rr)
            #pragma unroll
            for (int cx = 0; cx < 6; ++cx)
                sm[OP5 + ((oc * 8 + ic) * 6 + r0 + rr) * 6 + cx] = acc[rr][cx];
    }
    __syncthreads();
    // reduce over ic + pool + bias + relu -> f[90]
    if (tid < 90) {
        int oc = tid / 9, rem = tid % 9, py = rem / 3, px = rem % 3;
        float s00 = 0.f, s01 = 0.f, s10 = 0.f, s11 = 0.f;
        #pragma unroll
        for (int ic = 0; ic < 8; ++ic) {
            const float* p = &sm[OP5 + ((oc * 8 + ic) * 6 + 2 * py) * 6 + 2 * px];
            s00 += p[0]; s01 += p[1]; s10 += p[6]; s11 += p[7];
        }
        float m = fmaxf(fmaxf(s00, s01), fmaxf(s10, s11)) + kf_b2[oc];
        sm[OF + tid] = fmaxf(m, 0.f);
    }
    __syncthreads();

    // ---- fc 90->32 + relu ----
    if (tid < 32) {
        float acc = kf_fc1_b[tid];
        const float* wr = &kf_fc1_w[tid * 90];
        for (int i = 0; i < 90; ++i) acc = fmaf(wr[i], sm[OF + i], acc);
        sm[OH + tid] = fmaxf(acc, 0.f);
    }
    __syncthreads();

    // ---- fc 32->40 (dynamic kernels) ----
    if (tid < 40) {
        float acc = kf_fc2_b[tid];
        const float* wr = &kf_fc2_w[tid * 32];
        #pragma unroll
        for (int i = 0; i < 32; ++i) acc = fmaf(wr[i], sm[OH + i], acc);
        sm[OK2 + tid] = acc;
    }
    __syncthreads();

    // ---- dynamic 2x2 conv + pool + relu: thread = (oc, pooled row) ----
    if (tid < 130) {
        int oc = tid / 13, py = tid % 13;
        float k0 = sm[OK2 + oc * 4 + 0], k1 = sm[OK2 + oc * 4 + 1];
        float k2 = sm[OK2 + oc * 4 + 2], k3 = sm[OK2 + oc * 4 + 3];
        const float* x0 = &sm[OX + 2 * py * 28];
        const float* x1 = x0 + 28;
        const float* x2 = x0 + 56;
        float A0 = x0[0], A1 = x1[0], A2 = x2[0];
        float B0 = x0[1], B1 = x1[1], B2 = x2[1];
        #pragma unroll
        for (int j = 0; j < 13; ++j) {
            float C0 = x0[2 * j + 2], C1 = x1[2 * j + 2], C2 = x2[2 * j + 2];
            float c00 = A0 * k0 + B0 * k1 + A1 * k2 + B1 * k3;
            float c01 = B0 * k0 + C0 * k1 + B1 * k2 + C1 * k3;
            float c10 = A1 * k0 + B1 * k1 + A2 * k2 + B2 * k3;
            float c11 = B1 * k0 + C1 * k1 + B2 * k2 + C2 * k3;
            float m = fmaxf(fmaxf(c00, c01), fmaxf(c10, c11));
            sm[OY + oc * 169 + py * 13 + j] = fmaxf(m, 0.f);
            A0 = C0; A1 = C1; A2 = C2;
            if (j < 12) { B0 = x0[2 * j + 3]; B1 = x1[2 * j + 3]; B2 = x2[2 * j + 3]; }
        }
    }
    __syncthreads();

    // ---- conv2 5x5 [10,13,13]->[20,9,9]: thread = (oc, 3-row grp, col-half) ----
    // Full 10-ic per thread, bias folded into acc init -> writes c3 directly;
    // no partial region, no combine stage. col 4 double-written identically.
    if (tid < 120) {
        int oc = tid / 6, rem = tid % 6;
        int rg = rem / 2, ch = rem % 2;
        int r0 = 3 * rg, c0 = 4 * ch;
        float b = conv2_b[oc];
        float acc[3][5];
        #pragma unroll
        for (int r = 0; r < 3; ++r)
            #pragma unroll
            for (int i = 0; i < 5; ++i) acc[r][i] = b;
        for (int ic = 0; ic < 10; ++ic) {
            float w[25];
            const float* wg = conv2_w + (oc * 10 + ic) * 25;
            #pragma unroll
            for (int i = 0; i < 25; ++i) w[i] = wg[i];
            const float* yb = &sm[OY + ic * 169];
            #pragma unroll
            for (int u = 0; u < 7; ++u) {
                const float* ys = yb + (r0 + u) * 13 + c0;
                float row[9];
                #pragma unroll
                for (int i = 0; i < 9; ++i) row[i] = ys[i];
                #pragma unroll
                for (int rr = 0; rr < 3; ++rr) {
                    int ky = u - rr;
                    if (ky >= 0 && ky <= 4) {
                        #pragma unroll
                        for (int kx = 0; kx < 5; ++kx)
                            #pragma unroll
                            for (int cx = 0; cx < 5; ++cx)
                                acc[rr][cx] = fmaf(w[ky * 5 + kx], row[cx + kx], acc[rr][cx]);
                    }
                }
            }
        }
        #pragma unroll
        for (int rr = 0; rr < 3; ++rr)
            #pragma unroll
            for (int cx = 0; cx < 5; ++cx)
                sm[OC3 + oc * 81 + (r0 + rr) * 9 + c0 + cx] = acc[rr][cx];
    }
    __syncthreads();

    // ---- pool (9->4) + relu -> p3[20,4,4] ----
    for (int idx = tid; idx < 320; idx += TPB) {
        int oc = idx / 16, rem = idx % 16;
        int py = rem / 4, px = rem % 4;
        const float* c = &sm[OC3 + oc * 81 + (2 * py) * 9 + 2 * px];
        float m = fmaxf(fmaxf(c[0], c[1]), fmaxf(c[9], c[10]));
        sm[OP3 + idx] = fmaxf(m, 0.f);
    }
    __syncthreads();

    // ---- fc 320->50 + relu, 5-way k-split ----
    if (tid < 250) {
        int g = tid / 50, o = tid % 50;
        const float* wr = &fc1_w[o * 320 + g * 64];
        const float* pp = &sm[OP3 + g * 64];
        float acc = 0.f;
        #pragma unroll
        for (int i = 0; i < 64; ++i) acc = fmaf(wr[i], pp[i], acc);
        sm[OPF + tid] = acc;
    }
    __syncthreads();
    if (tid < 50) {
        float acc = fc1_b[tid];
        #pragma unroll
        for (int g = 0; g < 5; ++g) acc += sm[OPF + g * 50 + tid];
        sm[OA1 + tid] = fmaxf(acc, 0.f);
    }
    __syncthreads();

    // ---- fc 50->10 ----
    if (tid < 10) {
        float acc = fc2_b[tid];
        const float* wr = &fc2_w[tid * 50];
        #pragma unroll
        for (int i = 0; i < 50; ++i) acc = fmaf(wr[i], sm[OA1 + i], acc);
        sm[OZ + tid] = acc;
    }
    __syncthreads();

    // ---- log_softmax + store ----
    if (tid < 10) {
        float m = sm[OZ + 0];
        #pragma unroll
        for (int i = 1; i < 10; ++i) m = fmaxf(m, sm[OZ + i]);
        float s = 0.f;
        #pragma unroll
        for (int i = 0; i < 10; ++i) s += expf(sm[OZ + i] - m);
        out[n * 10 + tid] = sm[OZ + tid] - m - logf(s);
    }
}

extern "C" void kernel_launch(void* const* d_in, const int* in_sizes, int n_in,
                              void* d_out, int out_size, void* d_ws, size_t ws_size,
                              hipStream_t stream) {
    const float* x        = (const float*)d_in[0];
    const float* kf_w1    = (const float*)d_in[1];
    const float* kf_b1    = (const float*)d_in[2];
    const float* kf_w2    = (const float*)d_in[3];
    const float* kf_b2    = (const float*)d_in[4];
    const float* kf_fc1_w = (const float*)d_in[5];
    const float* kf_fc1_b = (const float*)d_in[6];
    const float* kf_fc2_w = (const float*)d_in[7];
    const float* kf_fc2_b = (const float*)d_in[8];
    const float* conv2_w  = (const float*)d_in[9];
    const float* conv2_b  = (const float*)d_in[10];
    const float* fc1_w    = (const float*)d_in[11];
    const float* fc1_b    = (const float*)d_in[12];
    const float* fc2_w    = (const float*)d_in[13];
    const float* fc2_b    = (const float*)d_in[14];

    const int N = in_sizes[0] / 784;   // 8192

    fused_forward<<<N, TPB, 0, stream>>>(
        x, kf_w1, kf_b1, kf_w2, kf_b2, kf_fc1_w, kf_fc1_b, kf_fc2_w, kf_fc2_b,
        conv2_w, conv2_b, fc1_w, fc1_b, fc2_w, fc2_b, (float*)d_out);
}

// Round 6
// 314.306 us; speedup vs baseline: 1.1164x; 1.1164x over previous
//
#include <hip/hip_runtime.h>
#include <math.h>

#define TPB 256

// ---- LDS layout (float offsets), lifetime-overlaid. Weights in GLOBAL/L2. ----
// phase A (conv7/conv5): x[0,784) c1[784,1752) P5[1752,4632) f/h/k[4632,4794)
// phase B (dyn):         x[0,784) y[784,2474) k alive
// phase C (conv2):       y[784,2474) P2[2474,5714)
// phase D (tail):        c3[0,1620) p3[1620,1940) pf[1940,2190) a1[2190) z[2240)
#define OX    0
#define OC1   784
#define OP5   1752
#define OF    4632
#define OH    4722
#define OK2   4754
#define OY    784
#define OP2   2474
#define OC3   0
#define OP3   1620
#define OPF   1940
#define OA1   2190
#define OZ    2240
#define SM_TOT 5714   // 22856 B -> 7 blocks/CU

// NOTE: no min-waves launch bound — R3 showed (256,5) forces VGPR=48 + scratch
// spill (WRITE_SIZE 0.5->237 MB). Natural allocation is ~52-60 VGPR.
// Lane maps put oc in the LOW lane bits: same-address lanes broadcast (free),
// distinct addresses get odd strides -> no bank conflicts (R5 had 16-way on x).
__global__ __launch_bounds__(TPB) void fused_forward(
    const float* __restrict__ x,
    const float* __restrict__ kf_w1, const float* __restrict__ kf_b1,
    const float* __restrict__ kf_w2, const float* __restrict__ kf_b2,
    const float* __restrict__ kf_fc1_w, const float* __restrict__ kf_fc1_b,
    const float* __restrict__ kf_fc2_w, const float* __restrict__ kf_fc2_b,
    const float* __restrict__ conv2_w, const float* __restrict__ conv2_b,
    const float* __restrict__ fc1_w, const float* __restrict__ fc1_b,
    const float* __restrict__ fc2_w, const float* __restrict__ fc2_b,
    float* __restrict__ out)
{
    __shared__ float sm[SM_TOT];
    const int tid = threadIdx.x;
    const int n = blockIdx.x;

    // ---- stage 0: stage x into LDS (float4) ----
    {
        const float4* xg = (const float4*)(x + (long long)n * 784);
        float4* d = (float4*)&sm[OX];
        for (int i = tid; i < 196; i += TPB) d[i] = xg[i];
    }
    __syncthreads();

    // ---- conv7 (28->22) + pool (->11) + relu ----
    // lane map: oc = tid&7 (8 lanes share every x address -> broadcast).
    // thread = (oc, py, col-half): 6 pooled outputs; halves overlap at px=5
    // with bitwise-identical values -> benign double write.
    if (tid < 176) {
        int oc = tid & 7;
        int r  = tid >> 3;          // 0..21
        int py = r >> 1;
        int h  = r & 1;
        int cc0 = 10 * h;
        float c[2][12];
        #pragma unroll
        for (int r2 = 0; r2 < 2; ++r2)
            #pragma unroll
            for (int i = 0; i < 12; ++i) c[r2][i] = 0.f;
        float wc[7], wp[7];
        const float* wg = kf_w1 + oc * 49;
        #pragma unroll
        for (int i = 0; i < 7; ++i) wc[i] = wg[i];
        #pragma unroll
        for (int t = 0; t < 8; ++t) {
            const float* xs = &sm[OX + (2 * py + t) * 28 + cc0];
            float row[18];
            #pragma unroll
            for (int i = 0; i < 18; ++i) row[i] = xs[i];
            if (t <= 6) {
                #pragma unroll
                for (int kx = 0; kx < 7; ++kx)
                    #pragma unroll
                    for (int cc = 0; cc < 12; ++cc)
                        c[0][cc] = fmaf(wc[kx], row[cc + kx], c[0][cc]);
            }
            if (t >= 1) {
                #pragma unroll
                for (int kx = 0; kx < 7; ++kx)
                    #pragma unroll
                    for (int cc = 0; cc < 12; ++cc)
                        c[1][cc] = fmaf(wp[kx], row[cc + kx], c[1][cc]);
            }
            #pragma unroll
            for (int i = 0; i < 7; ++i) wp[i] = wc[i];
            if (t < 7) {
                const float* wn = wg + (t + 1) * 7;
                #pragma unroll
                for (int i = 0; i < 7; ++i) wc[i] = wn[i];
            }
        }
        float b = kf_b1[oc];
        #pragma unroll
        for (int j = 0; j < 6; ++j) {
            float m = fmaxf(fmaxf(c[0][2 * j], c[0][2 * j + 1]),
                            fmaxf(c[1][2 * j], c[1][2 * j + 1]));
            sm[OC1 + oc * 121 + py * 11 + 5 * h + j] = fmaxf(m + b, 0.f);
        }
    }
    __syncthreads();

    // ---- conv5: thread = (row-half, oc, ic) computes 3x6 conv partial ----
    // ic in low lane bits: 8 distinct c1 addresses (stride 121 == 25 mod 32,
    // conflict-free) broadcast across the 10 oc groups.
    if (tid < 160) {
        int hh = tid / 80, rem = tid % 80;
        int oc = rem / 8, ic = rem % 8;
        int r0 = 3 * hh;
        float w[25];
        const float* wg = kf_w2 + (oc * 8 + ic) * 25;
        #pragma unroll
        for (int i = 0; i < 25; ++i) w[i] = wg[i];
        float acc[3][6];
        #pragma unroll
        for (int r = 0; r < 3; ++r)
            #pragma unroll
            for (int i = 0; i < 6; ++i) acc[r][i] = 0.f;
        const float* xb = &sm[OC1 + ic * 121];
        #pragma unroll
        for (int u = 0; u < 7; ++u) {
            const float* xs = xb + (r0 + u) * 11;
            float row[10];
            #pragma unroll
            for (int i = 0; i < 10; ++i) row[i] = xs[i];
            #pragma unroll
            for (int rr = 0; rr < 3; ++rr) {
                int ky = u - rr;
                if (ky >= 0 && ky <= 4) {
                    #pragma unroll
                    for (int kx = 0; kx < 5; ++kx)
                        #pragma unroll
                        for (int cx = 0; cx < 6; ++cx)
                            acc[rr][cx] = fmaf(w[ky * 5 + kx], row[cx + kx], acc[rr][cx]);
                }
            }
        }
        #pragma unroll
        for (int rr = 0; rr < 3; ++rr)
            #pragma unroll
            for (int cx = 0; cx < 6; ++cx)
                sm[OP5 + ((oc * 8 + ic) * 6 + r0 + rr) * 6 + cx] = acc[rr][cx];
    }
    __syncthreads();
    // reduce over ic + pool + bias + relu -> f[90]
    if (tid < 90) {
        int oc = tid / 9, rem = tid % 9, py = rem / 3, px = rem % 3;
        float s00 = 0.f, s01 = 0.f, s10 = 0.f, s11 = 0.f;
        #pragma unroll
        for (int ic = 0; ic < 8; ++ic) {
            const float* p = &sm[OP5 + ((oc * 8 + ic) * 6 + 2 * py) * 6 + 2 * px];
            s00 += p[0]; s01 += p[1]; s10 += p[6]; s11 += p[7];
        }
        float m = fmaxf(fmaxf(s00, s01), fmaxf(s10, s11)) + kf_b2[oc];
        sm[OF + tid] = fmaxf(m, 0.f);
    }
    __syncthreads();

    // ---- fc 90->32 + relu ----
    if (tid < 32) {
        float acc = kf_fc1_b[tid];
        const float* wr = &kf_fc1_w[tid * 90];
        for (int i = 0; i < 90; ++i) acc = fmaf(wr[i], sm[OF + i], acc);
        sm[OH + tid] = fmaxf(acc, 0.f);
    }
    __syncthreads();

    // ---- fc 32->40 (dynamic kernels) ----
    if (tid < 40) {
        float acc = kf_fc2_b[tid];
        const float* wr = &kf_fc2_w[tid * 32];
        #pragma unroll
        for (int i = 0; i < 32; ++i) acc = fmaf(wr[i], sm[OH + i], acc);
        sm[OK2 + tid] = acc;
    }
    __syncthreads();

    // ---- dynamic 2x2 conv + pool + relu ----
    // lane map: oc = tid%10 (10 lanes broadcast every x address; py groups have
    // stride 56 == 24 mod 32 but only ~7 distinct addrs/wave -> spread).
    if (tid < 130) {
        int oc = tid % 10, py = tid / 10;
        float k0 = sm[OK2 + oc * 4 + 0], k1 = sm[OK2 + oc * 4 + 1];
        float k2 = sm[OK2 + oc * 4 + 2], k3 = sm[OK2 + oc * 4 + 3];
        const float* x0 = &sm[OX + 2 * py * 28];
        const float* x1 = x0 + 28;
        const float* x2 = x0 + 56;
        float A0 = x0[0], A1 = x1[0], A2 = x2[0];
        float B0 = x0[1], B1 = x1[1], B2 = x2[1];
        #pragma unroll
        for (int j = 0; j < 13; ++j) {
            float C0 = x0[2 * j + 2], C1 = x1[2 * j + 2], C2 = x2[2 * j + 2];
            float c00 = A0 * k0 + B0 * k1 + A1 * k2 + B1 * k3;
            float c01 = B0 * k0 + C0 * k1 + B1 * k2 + C1 * k3;
            float c10 = A1 * k0 + B1 * k1 + A2 * k2 + B2 * k3;
            float c11 = B1 * k0 + C1 * k1 + B2 * k2 + C2 * k3;
            float m = fmaxf(fmaxf(c00, c01), fmaxf(c10, c11));
            sm[OY + oc * 169 + py * 13 + j] = fmaxf(m, 0.f);
            A0 = C0; A1 = C1; A2 = C2;
            if (j < 12) { B0 = x0[2 * j + 3]; B1 = x1[2 * j + 3]; B2 = x2[2 * j + 3]; }
        }
    }
    __syncthreads();

    // ---- conv2 5x5 [10,13,13]->[20,9,9], 2-way ic-split (R4 form) ----
    // lane map: oc = tid%20 -> 20 lanes broadcast every y address.
    if (tid < 120) {
        int oc = tid % 20, q = tid / 20;     // q in 0..5
        int h = q & 1, rg = q >> 1;
        int r0 = 3 * rg;
        float acc[3][9];
        #pragma unroll
        for (int r = 0; r < 3; ++r)
            #pragma unroll
            for (int i = 0; i < 9; ++i) acc[r][i] = 0.f;
        for (int icg = 0; icg < 5; ++icg) {
            int ic = 5 * h + icg;
            float w[25];
            const float* wg = conv2_w + (oc * 10 + ic) * 25;
            #pragma unroll
            for (int i = 0; i < 25; ++i) w[i] = wg[i];
            const float* yb = &sm[OY + ic * 169];
            #pragma unroll
            for (int u = 0; u < 7; ++u) {
                const float* ys = yb + (r0 + u) * 13;
                float row[13];
                #pragma unroll
                for (int i = 0; i < 13; ++i) row[i] = ys[i];
                #pragma unroll
                for (int rr = 0; rr < 3; ++rr) {
                    int ky = u - rr;
                    if (ky >= 0 && ky <= 4) {
                        #pragma unroll
                        for (int kx = 0; kx < 5; ++kx)
                            #pragma unroll
                            for (int cx = 0; cx < 9; ++cx)
                                acc[rr][cx] = fmaf(w[ky * 5 + kx], row[cx + kx], acc[rr][cx]);
                    }
                }
            }
        }
        #pragma unroll
        for (int rr = 0; rr < 3; ++rr)
            #pragma unroll
            for (int cx = 0; cx < 9; ++cx)
                sm[OP2 + h * 1620 + (oc * 9 + rg * 3 + rr) * 9 + cx] = acc[rr][cx];
    }
    __syncthreads();
    // combine ic-halves + bias -> c3 [20,9,9] at OC3 (x dead)
    if (tid < 180) {
        int oc = tid / 9, row = tid % 9;
        int base = (oc * 9 + row) * 9;
        float b = conv2_b[oc];
        #pragma unroll
        for (int cx = 0; cx < 9; ++cx)
            sm[OC3 + base + cx] = b + sm[OP2 + base + cx] + sm[OP2 + 1620 + base + cx];
    }
    __syncthreads();

    // ---- pool (9->4) + relu -> p3[20,4,4] ----
    if (tid < 320) {
        int oc = tid / 16, rem = tid % 16;
        int py = rem / 4, px = rem % 4;
        const float* c = &sm[OC3 + oc * 81 + (2 * py) * 9 + 2 * px];
        float m = fmaxf(fmaxf(c[0], c[1]), fmaxf(c[9], c[10]));
        sm[OP3 + tid] = fmaxf(m, 0.f);
    }
    __syncthreads();

    // ---- fc 320->50 + relu, 5-way k-split ----
    if (tid < 250) {
        int g = tid / 50, o = tid % 50;
        const float* wr = &fc1_w[o * 320 + g * 64];
        const float* pp = &sm[OP3 + g * 64];
        float acc = 0.f;
        #pragma unroll
        for (int i = 0; i < 64; ++i) acc = fmaf(wr[i], pp[i], acc);
        sm[OPF + tid] = acc;
    }
    __syncthreads();
    if (tid < 50) {
        float acc = fc1_b[tid];
        #pragma unroll
        for (int g = 0; g < 5; ++g) acc += sm[OPF + g * 50 + tid];
        sm[OA1 + tid] = fmaxf(acc, 0.f);
    }
    __syncthreads();

    // ---- fc 50->10 ----
    if (tid < 10) {
        float acc = fc2_b[tid];
        const float* wr = &fc2_w[tid * 50];
        #pragma unroll
        for (int i = 0; i < 50; ++i) acc = fmaf(wr[i], sm[OA1 + i], acc);
        sm[OZ + tid] = acc;
    }
    __syncthreads();

    // ---- log_softmax + store ----
    if (tid < 10) {
        float m = sm[OZ + 0];
        #pragma unroll
        for (int i = 1; i < 10; ++i) m = fmaxf(m, sm[OZ + i]);
        float s = 0.f;
        #pragma unroll
        for (int i = 0; i < 10; ++i) s += expf(sm[OZ + i] - m);
        out[n * 10 + tid] = sm[OZ + tid] - m - logf(s);
    }
}

extern "C" void kernel_launch(void* const* d_in, const int* in_sizes, int n_in,
                              void* d_out, int out_size, void* d_ws, size_t ws_size,
                              hipStream_t stream) {
    const float* x        = (const float*)d_in[0];
    const float* kf_w1    = (const float*)d_in[1];
    const float* kf_b1    = (const float*)d_in[2];
    const float* kf_w2    = (const float*)d_in[3];
    const float* kf_b2    = (const float*)d_in[4];
    const float* kf_fc1_w = (const float*)d_in[5];
    const float* kf_fc1_b = (const float*)d_in[6];
    const float* kf_fc2_w = (const float*)d_in[7];
    const float* kf_fc2_b = (const float*)d_in[8];
    const float* conv2_w  = (const float*)d_in[9];
    const float* conv2_b  = (const float*)d_in[10];
    const float* fc1_w    = (const float*)d_in[11];
    const float* fc1_b    = (const float*)d_in[12];
    const float* fc2_w    = (const float*)d_in[13];
    const float* fc2_b    = (const float*)d_in[14];

    const int N = in_sizes[0] / 784;   // 8192

    fused_forward<<<N, TPB, 0, stream>>>(
        x, kf_w1, kf_b1, kf_w2, kf_b2, kf_fc1_w, kf_fc1_b, kf_fc2_w, kf_fc2_b,
        conv2_w, conv2_b, fc1_w, fc1_b, fc2_w, fc2_b, (float*)d_out);
}

// Round 7
// 292.724 us; speedup vs baseline: 1.1987x; 1.0737x over previous
//
#include <hip/hip_runtime.h>
#include <math.h>

#define TPB 256

// ---- LDS layout (float offsets), lifetime-overlaid. Weights in GLOBAL/L2. ----
// x  [0,784)      alive load -> dyn
// c1 [784,1752)   conv7 out, dead after conv5
// y  [784,2474)   dyn out (over c1)
// P2 [2474,5074)  conv2 partials [2][20][8x8 pad65]
// f/h/k [5074..5236) KernelFinder tail (f written during conv5; k alive to dyn)
// p3 [0,320) pf [320,570) a1 [570,620) z [620,630)   (x dead)
#define OX    0
#define OC1   784
#define OY    784
#define OP2   2474
#define OF    5074
#define OH    5164
#define OK2   5196
#define OP3   0
#define OPF   320
#define OA1   570
#define OZ    620
#define SM_TOT 5236   // 20944 B -> 7 blocks/CU

// NOTE: no min-waves launch bound — R3 showed (256,5) forces VGPR=48 + scratch
// spill (WRITE_SIZE 0.5->237 MB).
// Lane maps keep oc in LOW lane bits: same-address lanes broadcast (free);
// R5->R6 cut SQ_LDS_BANK_CONFLICT 2.3e7 -> 3.9e6 this way.
__global__ __launch_bounds__(TPB) void fused_forward(
    const float* __restrict__ x,
    const float* __restrict__ kf_w1, const float* __restrict__ kf_b1,
    const float* __restrict__ kf_w2, const float* __restrict__ kf_b2,
    const float* __restrict__ kf_fc1_w, const float* __restrict__ kf_fc1_b,
    const float* __restrict__ kf_fc2_w, const float* __restrict__ kf_fc2_b,
    const float* __restrict__ conv2_w, const float* __restrict__ conv2_b,
    const float* __restrict__ fc1_w, const float* __restrict__ fc1_b,
    const float* __restrict__ fc2_w, const float* __restrict__ fc2_b,
    float* __restrict__ out)
{
    __shared__ float sm[SM_TOT];
    const int tid = threadIdx.x;
    const int n = blockIdx.x;

    // ---- stage 0: stage x into LDS (float4) ----
    {
        const float4* xg = (const float4*)(x + (long long)n * 784);
        float4* d = (float4*)&sm[OX];
        for (int i = tid; i < 196; i += TPB) d[i] = xg[i];
    }
    __syncthreads();

    // ---- conv7 (28->22) + pool (->11) + relu ----
    // lane map: oc = tid&7 -> 8-lane broadcast of every x address.
    if (tid < 176) {
        int oc = tid & 7;
        int r  = tid >> 3;
        int py = r >> 1;
        int h  = r & 1;
        int cc0 = 10 * h;
        float c[2][12];
        #pragma unroll
        for (int r2 = 0; r2 < 2; ++r2)
            #pragma unroll
            for (int i = 0; i < 12; ++i) c[r2][i] = 0.f;
        float wc[7], wp[7];
        const float* wg = kf_w1 + oc * 49;
        #pragma unroll
        for (int i = 0; i < 7; ++i) wc[i] = wg[i];
        #pragma unroll
        for (int t = 0; t < 8; ++t) {
            const float* xs = &sm[OX + (2 * py + t) * 28 + cc0];
            float row[18];
            #pragma unroll
            for (int i = 0; i < 18; ++i) row[i] = xs[i];
            if (t <= 6) {
                #pragma unroll
                for (int kx = 0; kx < 7; ++kx)
                    #pragma unroll
                    for (int cc = 0; cc < 12; ++cc)
                        c[0][cc] = fmaf(wc[kx], row[cc + kx], c[0][cc]);
            }
            if (t >= 1) {
                #pragma unroll
                for (int kx = 0; kx < 7; ++kx)
                    #pragma unroll
                    for (int cc = 0; cc < 12; ++cc)
                        c[1][cc] = fmaf(wp[kx], row[cc + kx], c[1][cc]);
            }
            #pragma unroll
            for (int i = 0; i < 7; ++i) wp[i] = wc[i];
            if (t < 7) {
                const float* wn = wg + (t + 1) * 7;
                #pragma unroll
                for (int i = 0; i < 7; ++i) wc[i] = wn[i];
            }
        }
        float b = kf_b1[oc];
        #pragma unroll
        for (int j = 0; j < 6; ++j) {
            float m = fmaxf(fmaxf(c[0][2 * j], c[0][2 * j + 1]),
                            fmaxf(c[1][2 * j], c[1][2 * j + 1]));
            sm[OC1 + oc * 121 + py * 11 + 5 * h + j] = fmaxf(m + b, 0.f);
        }
    }
    __syncthreads();

    // ---- conv5 (11->7) + pool (->3) + relu: full-depth, no partials ----
    // thread = (py,px,oc), oc = tid%10 -> 10-lane broadcast; 90 threads x 800 FMA.
    if (tid < 90) {
        int oc = tid % 10, r = tid / 10;
        int py = r / 3, px = r % 3;
        float a00 = 0.f, a01 = 0.f, a10 = 0.f, a11 = 0.f;
        for (int ic = 0; ic < 8; ++ic) {
            float w[25];
            const float* wg = kf_w2 + (oc * 8 + ic) * 25;
            #pragma unroll
            for (int i = 0; i < 25; ++i) w[i] = wg[i];
            const float* xb = &sm[OC1 + ic * 121 + 2 * py * 11 + 2 * px];
            float cur[6], nxt[6];
            #pragma unroll
            for (int i = 0; i < 6; ++i) cur[i] = xb[i];
            #pragma unroll
            for (int ky = 0; ky < 5; ++ky) {
                const float* xr = xb + (ky + 1) * 11;
                #pragma unroll
                for (int i = 0; i < 6; ++i) nxt[i] = xr[i];
                #pragma unroll
                for (int kx = 0; kx < 5; ++kx) {
                    float wv = w[ky * 5 + kx];
                    a00 = fmaf(wv, cur[kx],     a00);
                    a01 = fmaf(wv, cur[kx + 1], a01);
                    a10 = fmaf(wv, nxt[kx],     a10);
                    a11 = fmaf(wv, nxt[kx + 1], a11);
                }
                #pragma unroll
                for (int i = 0; i < 6; ++i) cur[i] = nxt[i];
            }
        }
        float m = fmaxf(fmaxf(a00, a01), fmaxf(a10, a11)) + kf_b2[oc];
        sm[OF + oc * 9 + py * 3 + px] = fmaxf(m, 0.f);
    }
    __syncthreads();

    // ---- fc 90->32 + relu, then fc 32->40: both wave 0, no barrier between
    // (intra-wave LDS ops are in-order; h written+read by the same wave).
    if (tid < 32) {
        float acc = kf_fc1_b[tid];
        const float* wr = &kf_fc1_w[tid * 90];
        for (int i = 0; i < 90; ++i) acc = fmaf(wr[i], sm[OF + i], acc);
        sm[OH + tid] = fmaxf(acc, 0.f);
    }
    if (tid < 40) {
        float acc = kf_fc2_b[tid];
        const float* wr = &kf_fc2_w[tid * 32];
        #pragma unroll
        for (int i = 0; i < 32; ++i) acc = fmaf(wr[i], sm[OH + i], acc);
        sm[OK2 + tid] = acc;
    }
    __syncthreads();

    // ---- dynamic 2x2 conv + pool + relu; oc = tid%10 broadcast map ----
    if (tid < 130) {
        int oc = tid % 10, py = tid / 10;
        float k0 = sm[OK2 + oc * 4 + 0], k1 = sm[OK2 + oc * 4 + 1];
        float k2 = sm[OK2 + oc * 4 + 2], k3 = sm[OK2 + oc * 4 + 3];
        const float* x0 = &sm[OX + 2 * py * 28];
        const float* x1 = x0 + 28;
        const float* x2 = x0 + 56;
        float A0 = x0[0], A1 = x1[0], A2 = x2[0];
        float B0 = x0[1], B1 = x1[1], B2 = x2[1];
        #pragma unroll
        for (int j = 0; j < 13; ++j) {
            float C0 = x0[2 * j + 2], C1 = x1[2 * j + 2], C2 = x2[2 * j + 2];
            float c00 = A0 * k0 + B0 * k1 + A1 * k2 + B1 * k3;
            float c01 = B0 * k0 + C0 * k1 + B1 * k2 + C1 * k3;
            float c10 = A1 * k0 + B1 * k1 + A2 * k2 + B2 * k3;
            float c11 = B1 * k0 + C1 * k1 + B2 * k2 + C2 * k3;
            float m = fmaxf(fmaxf(c00, c01), fmaxf(c10, c11));
            sm[OY + oc * 169 + py * 13 + j] = fmaxf(m, 0.f);
            A0 = C0; A1 = C1; A2 = C2;
            if (j < 12) { B0 = x0[2 * j + 3]; B1 = x1[2 * j + 3]; B2 = x2[2 * j + 3]; }
        }
    }
    __syncthreads();

    // ---- conv2 5x5: ONLY the 8x8 outputs the pool reads (row/col 8 discarded)
    // thread = (h2, rg4, oc20), oc = tid%20 broadcast; 2x8 tile, 5 ic each.
    // P2 padded: oc stride 65 -> conflict-free writes.
    if (tid < 160) {
        int oc = tid % 20, q = tid / 20;   // q 0..7
        int h = q & 1, rg = q >> 1;        // rg 0..3
        int r0 = 2 * rg;                   // output rows r0, r0+1
        float acc[2][8];
        #pragma unroll
        for (int r = 0; r < 2; ++r)
            #pragma unroll
            for (int i = 0; i < 8; ++i) acc[r][i] = 0.f;
        for (int icg = 0; icg < 5; ++icg) {
            int ic = 5 * h + icg;
            float w[25];
            const float* wg = conv2_w + (oc * 10 + ic) * 25;
            #pragma unroll
            for (int i = 0; i < 25; ++i) w[i] = wg[i];
            const float* yb = &sm[OY + ic * 169 + r0 * 13];
            #pragma unroll
            for (int u = 0; u < 6; ++u) {
                const float* ys = yb + u * 13;
                float row[12];
                #pragma unroll
                for (int i = 0; i < 12; ++i) row[i] = ys[i];
                #pragma unroll
                for (int rr = 0; rr < 2; ++rr) {
                    int ky = u - rr;
                    if (ky >= 0 && ky <= 4) {
                        #pragma unroll
                        for (int kx = 0; kx < 5; ++kx)
                            #pragma unroll
                            for (int cx = 0; cx < 8; ++cx)
                                acc[rr][cx] = fmaf(w[ky * 5 + kx], row[cx + kx], acc[rr][cx]);
                    }
                }
            }
        }
        #pragma unroll
        for (int rr = 0; rr < 2; ++rr)
            #pragma unroll
            for (int cx = 0; cx < 8; ++cx)
                sm[OP2 + h * 1300 + oc * 65 + (r0 + rr) * 8 + cx] = acc[rr][cx];
    }
    __syncthreads();

    // ---- fused combine(ic-halves)+bias+pool+relu -> p3[20,4,4] (320, looped) ----
    for (int idx = tid; idx < 320; idx += TPB) {
        int oc = idx / 16, rem = idx % 16;
        int py = rem / 4, px = rem % 4;
        int base = oc * 65 + (2 * py) * 8 + 2 * px;
        float b = conv2_b[oc];
        const float* p0 = &sm[OP2 + base];
        const float* p1 = &sm[OP2 + 1300 + base];
        float c00 = b + p0[0] + p1[0];
        float c01 = b + p0[1] + p1[1];
        float c10 = b + p0[8] + p1[8];
        float c11 = b + p0[9] + p1[9];
        float m = fmaxf(fmaxf(c00, c01), fmaxf(c10, c11));
        sm[OP3 + idx] = fmaxf(m, 0.f);
    }
    __syncthreads();

    // ---- fc 320->50, 5-way k-split ----
    if (tid < 250) {
        int g = tid / 50, o = tid % 50;
        const float* wr = &fc1_w[o * 320 + g * 64];
        const float* pp = &sm[OP3 + g * 64];
        float acc = 0.f;
        #pragma unroll
        for (int i = 0; i < 64; ++i) acc = fmaf(wr[i], pp[i], acc);
        sm[OPF + tid] = acc;
    }
    __syncthreads();

    // ---- tail: all wave 0, barrier-free (intra-wave LDS ordering) ----
    if (tid < 50) {
        float acc = fc1_b[tid];
        #pragma unroll
        for (int g = 0; g < 5; ++g) acc += sm[OPF + g * 50 + tid];
        sm[OA1 + tid] = fmaxf(acc, 0.f);
    }
    if (tid < 10) {
        float acc = fc2_b[tid];
        const float* wr = &fc2_w[tid * 50];
        #pragma unroll
        for (int i = 0; i < 50; ++i) acc = fmaf(wr[i], sm[OA1 + i], acc);
        sm[OZ + tid] = acc;
    }
    if (tid < 10) {
        float m = sm[OZ + 0];
        #pragma unroll
        for (int i = 1; i < 10; ++i) m = fmaxf(m, sm[OZ + i]);
        float s = 0.f;
        #pragma unroll
        for (int i = 0; i < 10; ++i) s += expf(sm[OZ + i] - m);
        out[n * 10 + tid] = sm[OZ + tid] - m - logf(s);
    }
}

extern "C" void kernel_launch(void* const* d_in, const int* in_sizes, int n_in,
                              void* d_out, int out_size, void* d_ws, size_t ws_size,
                              hipStream_t stream) {
    const float* x        = (const float*)d_in[0];
    const float* kf_w1    = (const float*)d_in[1];
    const float* kf_b1    = (const float*)d_in[2];
    const float* kf_w2    = (const float*)d_in[3];
    const float* kf_b2    = (const float*)d_in[4];
    const float* kf_fc1_w = (const float*)d_in[5];
    const float* kf_fc1_b = (const float*)d_in[6];
    const float* kf_fc2_w = (const float*)d_in[7];
    const float* kf_fc2_b = (const float*)d_in[8];
    const float* conv2_w  = (const float*)d_in[9];
    const float* conv2_b  = (const float*)d_in[10];
    const float* fc1_w    = (const float*)d_in[11];
    const float* fc1_b    = (const float*)d_in[12];
    const float* fc2_w    = (const float*)d_in[13];
    const float* fc2_b    = (const float*)d_in[14];

    const int N = in_sizes[0] / 784;   // 8192

    fused_forward<<<N, TPB, 0, stream>>>(
        x, kf_w1, kf_b1, kf_w2, kf_b2, kf_fc1_w, kf_fc1_b, kf_fc2_w, kf_fc2_b,
        conv2_w, conv2_b, fc1_w, fc1_b, fc2_w, fc2_b, (float*)d_out);
}